// Round 1
// baseline (229.750 us; speedup 1.0000x reference)
//
#include <hip/hip_runtime.h>

namespace {
constexpr int NB   = 16;      // batch
constexpr int NC   = 64;      // C0
constexpr int HW   = 128*128;
constexpr int SL   = 16384;   // L = H*W
constexpr int NG   = 8;       // G (token channels)
constexpr int DI   = 16;      // D_INNER
constexpr int NHD  = 2;       // NHEADS
constexpr int HD   = 8;       // HEADDIM
constexpr int DS   = 16;      // D_STATE
constexpr int CDIM = 48;      // CONV_DIM
constexpr int DP   = 66;      // D_IN_PROJ
constexpr int CQ   = 64;      // chunk size
constexpr int NCH  = SL/CQ;   // 256 chunks per batch

__global__ __launch_bounds__(256) void k_tok(
    const float* __restrict__ x, const float* __restrict__ w_tok,
    const float* __restrict__ b_tok, float* __restrict__ g0)
{
  __shared__ float wt[NG*NC];
  for (int i = threadIdx.x; i < NG*NC; i += 256) wt[i] = w_tok[i];
  __syncthreads();
  long idx = (long)blockIdx.x * 256 + threadIdx.x;   // b*SL + l
  int b = (int)(idx >> 14);
  int l = (int)(idx & (SL-1));
  float acc[NG];
  #pragma unroll
  for (int g = 0; g < NG; ++g) acc[g] = b_tok[g];
  const float* xp = x + (long)b*NC*HW + l;
  #pragma unroll 8
  for (int c = 0; c < NC; ++c) {
    float v = xp[(long)c*HW];
    #pragma unroll
    for (int g = 0; g < NG; ++g) acc[g] += v * wt[g*NC + c];
  }
  float* gp = g0 + idx*NG;
  #pragma unroll
  for (int g = 0; g < NG; ++g) gp[g] = acc[g];
}

// PASS 0: per-chunk state contribution S_c and decay P_c
// PASS 1: per-chunk outputs using incoming state -> gf
template<int PASS>
__global__ __launch_bounds__(256) void k_chunk(
    const float* __restrict__ g0, const float* __restrict__ w_in,
    const float* __restrict__ w_conv, const float* __restrict__ b_conv,
    const float* __restrict__ dt_bias, const float* __restrict__ A_log,
    const float* __restrict__ Dvec, const float* __restrict__ norm_w,
    const float* __restrict__ w_out,
    float* __restrict__ Sc, float* __restrict__ Pc,
    const float* __restrict__ Stin, float* __restrict__ gf)
{
  __shared__ float gs[CQ+2][NG];      // u halo: l0-2 .. l0+CQ-1
  __shared__ float win[DP][NG];
  __shared__ float wcv[CDIM][3];
  __shared__ float pre[CQ+2][CDIM];   // pre-conv xBC
  __shared__ float xs[CQ][17];        // post conv+silu: x (16)
  __shared__ float Bs[CQ][17];        // B (16)
  __shared__ float Cs[CQ][17];        // C (16)
  __shared__ float dts[CQ][NHD];
  __shared__ float csA[NHD][CQ];      // inclusive cumsum of A*dt
  __shared__ float ce[NHD][CQ];       // exp(csA)
  __shared__ float cf[NHD][CQ];       // exp(-csA)*dt

  int tid = threadIdx.x;
  int b  = blockIdx.x >> 8;
  int ch = blockIdx.x & (NCH-1);
  int l0 = ch*CQ;

  for (int i = tid; i < DP*NG; i += 256) win[i>>3][i&7] = w_in[i];
  for (int i = tid; i < CDIM*3; i += 256) wcv[i/3][i%3] = w_conv[i];
  for (int i = tid; i < (CQ+2)*NG; i += 256) {
    int t = i >> 3, g = i & 7;
    int l = l0 - 2 + t;
    gs[t][g] = (l >= 0) ? g0[((long)b*SL + l)*NG + g] : 0.f;
  }
  __syncthreads();

  // pre-conv xBC: pre[t][j] = u[l0-2+t] . w_in[16+j]
  for (int i = tid; i < (CQ+2)*CDIM; i += 256) {
    int t = i / CDIM, j = i % CDIM;
    float a = 0.f;
    #pragma unroll
    for (int g = 0; g < NG; ++g) a += gs[t][g]*win[DI + j][g];
    pre[t][j] = a;
  }
  // dt = softplus(u . w_in[64+h] + dt_bias)
  if (tid < CQ*NHD) {
    int t = tid >> 1, h = tid & 1;
    float a = dt_bias[h];
    #pragma unroll
    for (int g = 0; g < NG; ++g) a += gs[t+2][g]*win[64+h][g];
    dts[t][h] = (a > 20.f) ? a : log1pf(expf(a));
  }
  __syncthreads();

  // causal depthwise conv (taps pre[t],pre[t+1],pre[t+2]) + bias + silu
  for (int i = tid; i < CQ*CDIM; i += 256) {
    int t = i / CDIM, j = i % CDIM;
    float a = b_conv[j] + pre[t][j]*wcv[j][0] + pre[t+1][j]*wcv[j][1] + pre[t+2][j]*wcv[j][2];
    float s = a / (1.f + expf(-a));
    if (j < DI) xs[t][j] = s;
    else if (j < DI+DS) Bs[t][j-DI] = s;
    else Cs[t][j-DI-DS] = s;
  }
  __syncthreads();

  if (tid < NHD) {
    float A = -expf(A_log[tid]);
    float c = 0.f;
    for (int tt = 0; tt < CQ; ++tt) { c += A*dts[tt][tid]; csA[tid][tt] = c; }
  }
  __syncthreads();
  if (tid < NHD*CQ) {
    int h = tid >> 6, tt = tid & 63;
    float v = csA[h][tt];
    ce[h][tt] = expf(v);
    cf[h][tt] = expf(-v) * dts[tt][h];
  }
  __syncthreads();

  if constexpr (PASS == 0) {
    // S_c[h][p][n] = sum_s exp(csA_end - csA_s)*dt_s*x_s[h,p]*B_s[n]
    int h = tid >> 7, p = (tid >> 4) & 7, n = tid & 15;
    float ceend = ce[h][CQ-1];
    float acc = 0.f;
    for (int s = 0; s < CQ; ++s)
      acc += (ceend*cf[h][s]) * xs[s][h*HD+p] * Bs[s][n];
    Sc[((long)b*NCH + ch)*256 + tid] = acc;
    if (tid < NHD) Pc[((long)b*NCH + ch)*2 + tid] = ce[tid][CQ-1];
  } else {
    __shared__ float Gd[CQ][CQ+1];     // C_t . B_s
    __shared__ float stin_s[NHD*HD*DS];
    __shared__ float ylds[CQ][DI];

    for (int i = tid; i < NHD*HD*DS; i += 256)
      stin_s[i] = Stin[((long)b*NCH + ch)*256 + i];
    for (int i = tid; i < CQ*CQ; i += 256) {
      int t = i >> 6, s = i & (CQ-1);
      float a = 0.f;
      #pragma unroll
      for (int n = 0; n < DS; ++n) a += Cs[t][n]*Bs[s][n];
      Gd[t][s] = a;
    }
    __syncthreads();

    int t  = tid >> 2;
    int q4 = tid & 3;
    int h  = q4 >> 1;
    int pl = (q4 & 1)*4;       // p offset within head
    int pb = h*HD + pl;        // channel base
    float Dh  = Dvec[h];
    float cet = ce[h][t];
    float y[4];
    #pragma unroll
    for (int pp = 0; pp < 4; ++pp) {
      float a = 0.f;
      #pragma unroll
      for (int n = 0; n < DS; ++n) a += Cs[t][n]*stin_s[h*128 + (pl+pp)*16 + n];
      y[pp] = cet*a + Dh*xs[t][pb+pp];
    }
    for (int s = 0; s <= t; ++s) {
      float w = cet * cf[h][s] * Gd[t][s];
      #pragma unroll
      for (int pp = 0; pp < 4; ++pp) y[pp] += w * xs[s][pb+pp];
    }
    #pragma unroll
    for (int pp = 0; pp < 4; ++pp) ylds[t][pb+pp] = y[pp];
    __syncthreads();

    // epilogue: gate with silu(z), RMS norm, out-proj, +u residual
    if (tid < CQ) {
      float yv[DI]; float ssum = 0.f;
      #pragma unroll
      for (int d = 0; d < DI; ++d) {
        float zz = 0.f;
        #pragma unroll
        for (int g = 0; g < NG; ++g) zz += gs[tid+2][g]*win[d][g];
        float sz = zz / (1.f + expf(-zz));
        float v = ylds[tid][d] * sz;
        yv[d] = v; ssum += v*v;
      }
      float sc = rsqrtf(ssum*(1.f/DI) + 1e-5f);
      #pragma unroll
      for (int d = 0; d < DI; ++d) yv[d] *= sc * norm_w[d];
      long base = ((long)b*SL + l0 + tid)*NG;
      #pragma unroll
      for (int g = 0; g < NG; ++g) {
        float a = gs[tid+2][g];   // +u residual
        #pragma unroll
        for (int d = 0; d < DI; ++d) a += yv[d]*w_out[g*DI+d];
        gf[base+g] = a;
      }
    }
  }
}

__global__ __launch_bounds__(256) void k_scan(
    const float* __restrict__ Sc, const float* __restrict__ Pc,
    float* __restrict__ Stin)
{
  int b = blockIdx.x;
  int tid = threadIdx.x;           // h*128 + p*16 + n
  int h = tid >> 7;
  float st = 0.f;
  long base = (long)b * NCH;
  #pragma unroll 8
  for (int c = 0; c < NCH; ++c) {
    Stin[(base + c)*256 + tid] = st;
    st = st * Pc[(base + c)*2 + h] + Sc[(base + c)*256 + tid];
  }
}

__global__ __launch_bounds__(256) void k_detok(
    const float* __restrict__ x, const float* __restrict__ gf,
    const float* __restrict__ w_detok, const float* __restrict__ b_detok,
    float* __restrict__ out)
{
  __shared__ float wd[NC*NG];
  __shared__ float bd[NC];
  for (int i = threadIdx.x; i < NC*NG; i += 256) wd[i] = w_detok[i];
  if (threadIdx.x < NC) bd[threadIdx.x] = b_detok[threadIdx.x];
  __syncthreads();
  long idx = (long)blockIdx.x * 256 + threadIdx.x;   // b*SL + l
  int b = (int)(idx >> 14);
  int l = (int)(idx & (SL-1));
  float gv[NG];
  const float* gp = gf + idx*NG;
  #pragma unroll
  for (int g = 0; g < NG; ++g) gv[g] = gp[g];
  const float* xp = x + (long)b*NC*HW + l;
  float* op = out + (long)b*NC*HW + l;
  #pragma unroll
  for (int c = 0; c < NC; ++c) {
    float a = bd[c] + xp[(long)c*HW];
    #pragma unroll
    for (int g = 0; g < NG; ++g) a += gv[g]*wd[c*NG+g];
    op[(long)c*HW] = a;
  }
}
} // namespace

extern "C" void kernel_launch(void* const* d_in, const int* in_sizes, int n_in,
                              void* d_out, int out_size, void* d_ws, size_t ws_size,
                              hipStream_t stream)
{
  const float* x       = (const float*)d_in[0];
  const float* w_tok   = (const float*)d_in[1];
  const float* b_tok   = (const float*)d_in[2];
  const float* w_detok = (const float*)d_in[3];
  const float* b_detok = (const float*)d_in[4];
  const float* w_in    = (const float*)d_in[5];
  const float* w_conv  = (const float*)d_in[6];
  const float* b_conv  = (const float*)d_in[7];
  const float* dt_bias = (const float*)d_in[8];
  const float* A_log   = (const float*)d_in[9];
  const float* Dvec    = (const float*)d_in[10];
  const float* norm_w  = (const float*)d_in[11];
  const float* w_out   = (const float*)d_in[12];
  float* out = (float*)d_out;

  float* ws   = (float*)d_ws;
  float* g0   = ws;                        // NB*SL*NG      = 2,097,152 f
  float* gf   = g0 + (long)NB*SL*NG;       // 2,097,152 f
  float* Sc   = gf + (long)NB*SL*NG;       // NB*NCH*256    = 1,048,576 f
  float* Pc   = Sc + (long)NB*NCH*256;     // NB*NCH*2      = 8,192 f
  float* Stin = Pc + (long)NB*NCH*2;       // 1,048,576 f   (total ~25 MB)

  k_tok<<<NB*SL/256, 256, 0, stream>>>(x, w_tok, b_tok, g0);
  k_chunk<0><<<NB*NCH, 256, 0, stream>>>(g0, w_in, w_conv, b_conv, dt_bias,
                                         A_log, Dvec, norm_w, w_out,
                                         Sc, Pc, nullptr, nullptr);
  k_scan<<<NB, 256, 0, stream>>>(Sc, Pc, Stin);
  k_chunk<1><<<NB*NCH, 256, 0, stream>>>(g0, w_in, w_conv, b_conv, dt_bias,
                                         A_log, Dvec, norm_w, w_out,
                                         Sc, Pc, Stin, gf);
  k_detok<<<NB*SL/256, 256, 0, stream>>>(x, gf, w_detok, b_detok, out);
}

// Round 2
// 202.039 us; speedup vs baseline: 1.1372x; 1.1372x over previous
//
#include <hip/hip_runtime.h>

namespace {
constexpr int NB   = 16;
constexpr int NC   = 64;
constexpr int HW   = 128*128;
constexpr int SL   = 16384;
constexpr int NG   = 8;
constexpr int DI   = 16;
constexpr int NHD  = 2;
constexpr int DS   = 16;
constexpr int CDIM = 48;
constexpr int DP   = 66;
constexpr int CQ   = 64;
constexpr int NCH  = SL/CQ;   // 256
constexpr int WCH  = 4;       // chunks (waves) per block

__device__ __forceinline__ float frcp(float x){
#if __has_builtin(__builtin_amdgcn_rcpf)
  return __builtin_amdgcn_rcpf(x);
#else
  return 1.0f/x;
#endif
}
__device__ __forceinline__ float rl(float v, int s){
  return __int_as_float(__builtin_amdgcn_readlane(__float_as_int(v), s));
}
__device__ __forceinline__ float sigu(float a){ return frcp(1.0f + __expf(-a)); }

__global__ __launch_bounds__(256) void k_tok(
    const float* __restrict__ x, const float* __restrict__ w_tok,
    const float* __restrict__ b_tok, float* __restrict__ g0)
{
  __shared__ float wt[NG*NC];
  for (int i = threadIdx.x; i < NG*NC; i += 256) wt[i] = w_tok[i];
  __syncthreads();
  long idx = (long)blockIdx.x * 256 + threadIdx.x;
  int b = (int)(idx >> 14);
  int l = (int)(idx & (SL-1));
  float acc[NG];
  #pragma unroll
  for (int g = 0; g < NG; ++g) acc[g] = b_tok[g];
  const float* xp = x + (long)b*NC*HW + l;
  #pragma unroll 8
  for (int c = 0; c < NC; ++c) {
    float v = xp[(long)c*HW];
    #pragma unroll
    for (int g = 0; g < NG; ++g) acc[g] += v * wt[g*NC + c];
  }
  float* gp = g0 + idx*NG;
  *(float4*)gp     = make_float4(acc[0],acc[1],acc[2],acc[3]);
  *(float4*)(gp+4) = make_float4(acc[4],acc[5],acc[6],acc[7]);
}

// PASS 0: per-chunk state contribution Sc + decay Pc.  PASS 1: outputs -> gf.
template<int PASS>
__global__ __launch_bounds__(256) void k_chunk(
    const float* __restrict__ g0, const float* __restrict__ w_in,
    const float* __restrict__ w_conv, const float* __restrict__ b_conv,
    const float* __restrict__ dt_bias, const float* __restrict__ A_log,
    const float* __restrict__ Dvec, const float* __restrict__ norm_w,
    const float* __restrict__ w_out,
    float* __restrict__ Sc, float* __restrict__ Pc,
    const float* __restrict__ Stin, float* __restrict__ gf)
{
  constexpr int JMAX = (PASS==1) ? CDIM : 32;        // PASS0 needs x,B only
  constexpr int SLAB = (PASS==0) ? CQ*36 : 256;      // f32 per wave
  __shared__ float s_win[DP*NG];
  __shared__ float s_wc0[CDIM], s_wc1[CDIM], s_wc2[CDIM], s_bc[CDIM];
  __shared__ float s_wout[NG*DI];
  __shared__ float s_nw[DI];
  __shared__ float s_misc[6];                // A0,A1,dtb0,dtb1,D0,D1
  __shared__ float s_halo[WCH*2*CDIM];       // pre at chunk-start-2, -1
  __shared__ float s_big[WCH*SLAB];

  int tid = threadIdx.x, lane = tid & 63, wave = tid >> 6;

  for (int i = tid; i < DP*NG; i += 256) s_win[i] = w_in[i];
  if (tid < CDIM) {
    s_wc0[tid] = w_conv[tid*3];  s_wc1[tid] = w_conv[tid*3+1];
    s_wc2[tid] = w_conv[tid*3+2]; s_bc[tid] = b_conv[tid];
  }
  if (tid < NG*DI) s_wout[tid] = w_out[tid];
  if (tid < DI)    s_nw[tid]   = norm_w[tid];
  if (tid < NHD) {
    s_misc[tid]   = -__expf(A_log[tid]);
    s_misc[2+tid] = dt_bias[tid];
    s_misc[4+tid] = Dvec[tid];
  }
  __syncthreads();

  int b   = blockIdx.x >> 6;                  // NCH/WCH = 64 blocks/batch
  int chB = (blockIdx.x & 63)*WCH + wave;
  long cg = (long)b*NCH + chB;
  int l0  = chB*CQ;
  long pos = (long)b*SL + l0 + lane;

  float u[8];
  { const float* up = g0 + pos*NG;
    float4 a = *(const float4*)up, c = *(const float4*)(up+4);
    u[0]=a.x;u[1]=a.y;u[2]=a.z;u[3]=a.w;u[4]=c.x;u[5]=c.y;u[6]=c.z;u[7]=c.w; }

  if constexpr (PASS==1) {   // stage incoming state early (hide latency)
    float4 sv = *(const float4*)(Stin + cg*256 + lane*4);
    *(float4*)&s_big[wave*SLAB + lane*4] = sv;
  }

  // ---- in-proj for conv channels ----
  float pre[JMAX];
  #pragma unroll
  for (int j = 0; j < JMAX; ++j) {
    float a = 0.f;
    #pragma unroll
    for (int g = 0; g < NG; ++g) a += u[g]*s_win[(DI+j)*NG+g];
    pre[j] = a;
  }
  // halo handoff: lanes 62,63 of wave w feed wave w+1
  if (lane >= 62 && wave < WCH-1) {
    #pragma unroll
    for (int j = 0; j < JMAX; ++j)
      s_halo[((wave+1)*2 + (lane-62))*CDIM + j] = pre[j];
  }
  // wave 0 computes its own halo (previous chunk's last 2 positions)
  if (wave == 0 && lane < 2) {
    float uh[8];
    int hl = l0 - 2 + lane;
    if (hl >= 0) {
      const float* hp2 = g0 + ((long)b*SL + hl)*NG;
      float4 a = *(const float4*)hp2, c = *(const float4*)(hp2+4);
      uh[0]=a.x;uh[1]=a.y;uh[2]=a.z;uh[3]=a.w;uh[4]=c.x;uh[5]=c.y;uh[6]=c.z;uh[7]=c.w;
    } else {
      #pragma unroll
      for (int g = 0; g < 8; ++g) uh[g] = 0.f;
    }
    #pragma unroll
    for (int j = 0; j < JMAX; ++j) {
      float a = 0.f;
      #pragma unroll
      for (int g = 0; g < NG; ++g) a += uh[g]*s_win[(DI+j)*NG+g];
      s_halo[lane*CDIM + j] = a;
    }
  }
  __syncthreads();

  // ---- causal conv + bias + silu (shuffle neighbors) ----
  float xv[16], Bv[16];
  float Cvr[(PASS==1) ? 16 : 1];
  const float* hwp = &s_halo[wave*2*CDIM];
  #pragma unroll
  for (int j = 0; j < JMAX; ++j) {
    float h0 = hwp[j], h1 = hwp[CDIM + j];
    float pm1 = __shfl_up(pre[j], 1);
    float pm2 = __shfl_up(pre[j], 2);
    pm1 = (lane == 0) ? h1 : pm1;
    pm2 = (lane == 0) ? h0 : ((lane == 1) ? h1 : pm2);
    float a = s_bc[j] + pm2*s_wc0[j] + pm1*s_wc1[j] + pre[j]*s_wc2[j];
    float sv2 = a * sigu(a);
    if (j < 16) xv[j] = sv2;
    else if (j < 32) Bv[j-16] = sv2;
    else { if constexpr (PASS==1) Cvr[j-32] = sv2; }
  }

  // ---- dt (softplus) + per-lane cumsum of A*dt via shuffle prefix ----
  float dt0, dt1;
  { float a = s_misc[2];
    #pragma unroll
    for (int g = 0; g < NG; ++g) a += u[g]*s_win[64*NG+g];
    dt0 = (a > 20.f) ? a : log1pf(__expf(a));
    float b2 = s_misc[3];
    #pragma unroll
    for (int g = 0; g < NG; ++g) b2 += u[g]*s_win[65*NG+g];
    dt1 = (b2 > 20.f) ? b2 : log1pf(__expf(b2)); }
  float c0 = s_misc[0]*dt0, c1 = s_misc[1]*dt1;
  #pragma unroll
  for (int off = 1; off < 64; off <<= 1) {
    float t0 = __shfl_up(c0, off), t1 = __shfl_up(c1, off);
    if (lane >= off) { c0 += t0; c1 += t1; }
  }
  float ce0 = __expf(c0), ce1 = __expf(c1);
  float cf0 = __expf(-c0)*dt0, cf1 = __expf(-c1)*dt1;
  float cee0 = rl(ce0, 63), cee1 = rl(ce1, 63);

  if constexpr (PASS==0) {
    // transpose x,B,weights into wave slab; lanes re-map to (hp, n-quad)
    float* slab = &s_big[wave*SLAB + lane*36];
    #pragma unroll
    for (int k = 0; k < 16; ++k) { slab[k] = xv[k]; slab[16+k] = Bv[k]; }
    slab[32] = cee0*cf0; slab[33] = cee1*cf1;
    __builtin_amdgcn_wave_barrier();
    int hp = lane >> 2, nb = lane & 3, h = hp >> 3;
    float a0=0.f, a1=0.f, a2=0.f, a3=0.f;
    const float* base = &s_big[wave*SLAB];
    #pragma unroll 4
    for (int s = 0; s < CQ; ++s) {
      const float* sl = base + s*36;
      float t = sl[32+h] * sl[hp];
      float4 B4 = *(const float4*)&sl[16 + nb*4];
      a0 += t*B4.x; a1 += t*B4.y; a2 += t*B4.z; a3 += t*B4.w;
    }
    *(float4*)(Sc + cg*256 + hp*16 + nb*4) = make_float4(a0,a1,a2,a3);
    if (lane == 0) { Pc[cg*2] = cee0; Pc[cg*2+1] = cee1; }
  } else {
    // ---- intra-chunk quadratic scan via readlane broadcasts ----
    float y[16];
    float D0 = s_misc[4], D1 = s_misc[5];
    #pragma unroll
    for (int p = 0; p < 8; ++p) { y[p] = D0*xv[p]; y[8+p] = D1*xv[8+p]; }
    #pragma unroll 2
    for (int s = 0; s < CQ; ++s) {
      float ga = 0.f, gb = 0.f;
      #pragma unroll
      for (int n = 0; n < 8; ++n)  ga += Cvr[n]  * rl(Bv[n],  s);
      #pragma unroll
      for (int n = 0; n < 8; ++n)  gb += Cvr[8+n]* rl(Bv[8+n],s);
      float gg = ga + gb;
      float wA = ce0 * (rl(cf0,s) * gg);
      float wB = ce1 * (rl(cf1,s) * gg);
      bool ok = (s <= lane);
      wA = ok ? wA : 0.f; wB = ok ? wB : 0.f;
      #pragma unroll
      for (int p = 0; p < 8; ++p) {
        y[p]   += wA * rl(xv[p],   s);
        y[8+p] += wB * rl(xv[8+p], s);
      }
    }
    // ---- inter-chunk contribution from staged state ----
    const float* st = &s_big[wave*SLAB];
    #pragma unroll
    for (int hp = 0; hp < 16; ++hp) {
      float a = 0.f;
      #pragma unroll
      for (int n = 0; n < 16; ++n) a += Cvr[n]*st[hp*16+n];
      y[hp] += ((hp < 8) ? ce0 : ce1) * a;
    }
    // ---- gate, RMS norm, out-proj, +u residual ----
    float yv[16]; float ss = 0.f;
    #pragma unroll
    for (int d = 0; d < 16; ++d) {
      float zz = 0.f;
      #pragma unroll
      for (int g = 0; g < NG; ++g) zz += u[g]*s_win[d*NG+g];
      float v = y[d] * (zz * sigu(zz));
      yv[d] = v; ss += v*v;
    }
    float scn = rsqrtf(ss*(1.f/DI) + 1e-5f);
    #pragma unroll
    for (int d = 0; d < 16; ++d) yv[d] *= scn * s_nw[d];
    float og[8];
    #pragma unroll
    for (int g = 0; g < 8; ++g) {
      float a = u[g];
      #pragma unroll
      for (int d = 0; d < 16; ++d) a += yv[d]*s_wout[g*DI+d];
      og[g] = a;
    }
    float* gp = gf + pos*NG;
    *(float4*)gp     = make_float4(og[0],og[1],og[2],og[3]);
    *(float4*)(gp+4) = make_float4(og[4],og[5],og[6],og[7]);
  }
}

__global__ __launch_bounds__(256) void k_scan(
    const float* __restrict__ Sc, const float* __restrict__ Pc,
    float* __restrict__ Stin)
{
  int b = blockIdx.x;
  int tid = threadIdx.x;           // hp*16 + n
  int h = tid >> 7;
  float st = 0.f;
  long base = (long)b * NCH;
  #pragma unroll 8
  for (int c = 0; c < NCH; ++c) {
    Stin[(base + c)*256 + tid] = st;
    st = st * Pc[(base + c)*2 + h] + Sc[(base + c)*256 + tid];
  }
}

__global__ __launch_bounds__(256) void k_detok(
    const float* __restrict__ x, const float* __restrict__ gf,
    const float* __restrict__ w_detok, const float* __restrict__ b_detok,
    float* __restrict__ out)
{
  __shared__ float wd[NC*NG];
  __shared__ float bd[NC];
  for (int i = threadIdx.x; i < NC*NG; i += 256) wd[i] = w_detok[i];
  if (threadIdx.x < NC) bd[threadIdx.x] = b_detok[threadIdx.x];
  __syncthreads();
  long idx = (long)blockIdx.x * 256 + threadIdx.x;
  int b = (int)(idx >> 14);
  int l = (int)(idx & (SL-1));
  float gv[NG];
  const float* gp = gf + idx*NG;
  { float4 a = *(const float4*)gp, c = *(const float4*)(gp+4);
    gv[0]=a.x;gv[1]=a.y;gv[2]=a.z;gv[3]=a.w;gv[4]=c.x;gv[5]=c.y;gv[6]=c.z;gv[7]=c.w; }
  const float* xp = x + (long)b*NC*HW + l;
  float* op = out + (long)b*NC*HW + l;
  #pragma unroll
  for (int c = 0; c < NC; ++c) {
    float a = bd[c] + xp[(long)c*HW];
    #pragma unroll
    for (int g = 0; g < NG; ++g) a += gv[g]*wd[c*NG+g];
    op[(long)c*HW] = a;
  }
}
} // namespace

extern "C" void kernel_launch(void* const* d_in, const int* in_sizes, int n_in,
                              void* d_out, int out_size, void* d_ws, size_t ws_size,
                              hipStream_t stream)
{
  const float* x       = (const float*)d_in[0];
  const float* w_tok   = (const float*)d_in[1];
  const float* b_tok   = (const float*)d_in[2];
  const float* w_detok = (const float*)d_in[3];
  const float* b_detok = (const float*)d_in[4];
  const float* w_in    = (const float*)d_in[5];
  const float* w_conv  = (const float*)d_in[6];
  const float* b_conv  = (const float*)d_in[7];
  const float* dt_bias = (const float*)d_in[8];
  const float* A_log   = (const float*)d_in[9];
  const float* Dvec    = (const float*)d_in[10];
  const float* norm_w  = (const float*)d_in[11];
  const float* w_out   = (const float*)d_in[12];
  float* out = (float*)d_out;

  float* ws   = (float*)d_ws;
  float* g0   = ws;
  float* gf   = g0 + (long)NB*SL*NG;
  float* Sc   = gf + (long)NB*SL*NG;
  float* Pc   = Sc + (long)NB*NCH*256;
  float* Stin = Pc + (long)NB*NCH*2;

  k_tok<<<NB*SL/256, 256, 0, stream>>>(x, w_tok, b_tok, g0);
  k_chunk<0><<<NB*NCH/WCH, 256, 0, stream>>>(g0, w_in, w_conv, b_conv, dt_bias,
                                             A_log, Dvec, norm_w, w_out,
                                             Sc, Pc, nullptr, nullptr);
  k_scan<<<NB, 256, 0, stream>>>(Sc, Pc, Stin);
  k_chunk<1><<<NB*NCH/WCH, 256, 0, stream>>>(g0, w_in, w_conv, b_conv, dt_bias,
                                             A_log, Dvec, norm_w, w_out,
                                             Sc, Pc, Stin, gf);
  k_detok<<<NB*SL/256, 256, 0, stream>>>(x, gf, w_detok, b_detok, out);
}

// Round 3
// 158.282 us; speedup vs baseline: 1.4515x; 1.2764x over previous
//
#include <hip/hip_runtime.h>

namespace {
constexpr int NB   = 16;
constexpr int NC   = 64;
constexpr int HW   = 128*128;
constexpr int SL   = 16384;
constexpr int NG   = 8;
constexpr int DS   = 16;
constexpr int CQ   = 64;
constexpr int NCH  = SL/CQ;   // 256
constexpr int WCH  = 4;       // chunks (waves) per block

__device__ __forceinline__ float frcp(float x){ return __builtin_amdgcn_rcpf(x); }
__device__ __forceinline__ float rl(float v, int s){
  return __int_as_float(__builtin_amdgcn_readlane(__float_as_int(v), s));
}
__device__ __forceinline__ float sigu(float a){ return frcp(1.0f + __expf(-a)); }

__global__ __launch_bounds__(256) void k_tok(
    const float* __restrict__ x, const float* __restrict__ w_tok,
    const float* __restrict__ b_tok, float* __restrict__ g0)
{
  long idx = (long)blockIdx.x * 256 + threadIdx.x;
  int b = (int)(idx >> 14);
  int l = (int)(idx & (SL-1));
  float acc[8];
  #pragma unroll
  for (int g = 0; g < 8; ++g) acc[g] = b_tok[g];
  const float* xp = x + (long)b*NC*HW + l;
  #pragma unroll 8
  for (int c = 0; c < NC; ++c) {
    float v = xp[(long)c*HW];
    #pragma unroll
    for (int g = 0; g < 8; ++g) acc[g] += v * w_tok[g*NC + c];   // uniform -> s_load
  }
  float* gp = g0 + idx*8;
  *(float4*)gp     = make_float4(acc[0],acc[1],acc[2],acc[3]);
  *(float4*)(gp+4) = make_float4(acc[4],acc[5],acc[6],acc[7]);
}

// PASS 0: per-chunk state contribution Sc + decay Pc.  PASS 1: outputs -> gf.
template<int PASS>
__global__ __launch_bounds__(256, 4) void k_chunk(
    const float* __restrict__ g0, const float* __restrict__ w_in,
    const float* __restrict__ w_conv, const float* __restrict__ b_conv,
    const float* __restrict__ dt_bias, const float* __restrict__ A_log,
    const float* __restrict__ Dvec, const float* __restrict__ norm_w,
    const float* __restrict__ w_out,
    float* __restrict__ Sc, float* __restrict__ Pc,
    const float* __restrict__ Stin, float* __restrict__ gf)
{
  constexpr int JMAX = (PASS==1) ? 48 : 32;      // PASS0 needs x,B only
  __shared__ float s_big[(PASS==0) ? WCH*CQ*36 : 1];

  int tid = threadIdx.x, lane = tid & 63, wave = tid >> 6;
  int b   = blockIdx.x >> 6;
  int chB = (blockIdx.x & 63)*WCH + wave;
  long cg = (long)b*NCH + chB;
  int l0  = chB*CQ;
  long pos = (long)b*SL + l0 + lane;

  // own u (coalesced)
  float u[8];
  { const float* up = g0 + pos*8;
    float4 a = *(const float4*)up, c = *(const float4*)(up+4);
    u[0]=a.x;u[1]=a.y;u[2]=a.z;u[3]=a.w;u[4]=c.x;u[5]=c.y;u[6]=c.z;u[7]=c.w; }

  // stage incoming state into regs early (PASS1)
  float sv[4] = {0.f,0.f,0.f,0.f};
  if constexpr (PASS==1) {
    float4 t = *(const float4*)(Stin + cg*256 + lane*4);
    sv[0]=t.x; sv[1]=t.y; sv[2]=t.z; sv[3]=t.w;
  }

  // ---- halo pre-values in registers (no LDS, no barrier) ----
  // hA: lane = p*32 + j   (p in {0,1} = pos l0-2+p, j in 0..31)
  // hB: lane = p*16 + (j-32)  for j in 32..47 (PASS1 only; lanes 0..31)
  float hA = 0.f, hB = 0.f;
  {
    int pA = lane >> 5, jA = lane & 31;
    int hlA = l0 - 2 + pA;
    float uA[8] = {0,0,0,0,0,0,0,0};
    if (hlA >= 0) {
      const float* hp2 = g0 + ((long)b*SL + hlA)*8;
      float4 a = *(const float4*)hp2, c = *(const float4*)(hp2+4);
      uA[0]=a.x;uA[1]=a.y;uA[2]=a.z;uA[3]=a.w;uA[4]=c.x;uA[5]=c.y;uA[6]=c.z;uA[7]=c.w;
    }
    #pragma unroll
    for (int g = 0; g < 8; ++g) hA += uA[g]*w_in[(16+jA)*8+g];  // divergent row: vector load, L1-hot
    if constexpr (PASS==1) {
      int pB = (lane >> 4) & 1, jB = 32 + (lane & 15);
      int hlB = l0 - 2 + pB;
      float uB[8] = {0,0,0,0,0,0,0,0};
      if (hlB >= 0) {
        const float* hp2 = g0 + ((long)b*SL + hlB)*8;
        float4 a = *(const float4*)hp2, c = *(const float4*)(hp2+4);
        uB[0]=a.x;uB[1]=a.y;uB[2]=a.z;uB[3]=a.w;uB[4]=c.x;uB[5]=c.y;uB[6]=c.z;uB[7]=c.w;
      }
      #pragma unroll
      for (int g = 0; g < 8; ++g) hB += uB[g]*w_in[(16+jB)*8+g];
    }
  }

  // ---- blocked in-proj + causal conv + silu (weights via s_load) ----
  float xv[16], Bv[16];
  float Cvr[(PASS==1) ? 16 : 1];
  #pragma unroll
  for (int jb = 0; jb < JMAX/8; ++jb) {
    float pr[8];
    #pragma unroll
    for (int jj = 0; jj < 8; ++jj) {
      int j = jb*8 + jj;
      float a = 0.f;
      #pragma unroll
      for (int g = 0; g < 8; ++g) a += u[g]*w_in[(16+j)*8+g];   // uniform -> s_load
      pr[jj] = a;
    }
    #pragma unroll
    for (int jj = 0; jj < 8; ++jj) {
      int j = jb*8 + jj;
      float pm1 = __shfl_up(pr[jj], 1);
      float pm2 = __shfl_up(pr[jj], 2);
      float h0j = (j < 32) ? rl(hA, j)      : rl(hB, j-32);
      float h1j = (j < 32) ? rl(hA, 32+j)   : rl(hB, 16+(j-32));
      pm1 = (lane == 0) ? h1j : pm1;
      pm2 = (lane == 0) ? h0j : ((lane == 1) ? h1j : pm2);
      float a = b_conv[j] + pm2*w_conv[j*3] + pm1*w_conv[j*3+1] + pr[jj]*w_conv[j*3+2];
      float s = a * sigu(a);
      if (j < 16) xv[j] = s;
      else if (j < 32) Bv[j-16] = s;
      else { if constexpr (PASS==1) Cvr[j-32] = s; }
    }
  }

  // ---- dt (softplus) + cumsum of A*dt via shuffle prefix ----
  float dt0, dt1;
  { float a = dt_bias[0];
    #pragma unroll
    for (int g = 0; g < 8; ++g) a += u[g]*w_in[64*8+g];
    dt0 = (a > 20.f) ? a : log1pf(__expf(a));
    float b2 = dt_bias[1];
    #pragma unroll
    for (int g = 0; g < 8; ++g) b2 += u[g]*w_in[65*8+g];
    dt1 = (b2 > 20.f) ? b2 : log1pf(__expf(b2)); }
  float A0 = -__expf(A_log[0]), A1 = -__expf(A_log[1]);
  float c0 = A0*dt0, c1 = A1*dt1;
  #pragma unroll
  for (int off = 1; off < 64; off <<= 1) {
    float t0 = __shfl_up(c0, off), t1 = __shfl_up(c1, off);
    if (lane >= off) { c0 += t0; c1 += t1; }
  }
  float ce0 = __expf(c0), ce1 = __expf(c1);
  float cf0 = __expf(-c0)*dt0, cf1 = __expf(-c1)*dt1;
  float cee0 = rl(ce0, 63), cee1 = rl(ce1, 63);

  if constexpr (PASS==0) {
    float* slab = &s_big[wave*CQ*36 + lane*36];
    #pragma unroll
    for (int k = 0; k < 16; ++k) { slab[k] = xv[k]; slab[16+k] = Bv[k]; }
    slab[32] = cee0*cf0; slab[33] = cee1*cf1;
    __builtin_amdgcn_wave_barrier();
    int hp = lane >> 2, nb = lane & 3, h = hp >> 3;
    float a0=0.f, a1=0.f, a2=0.f, a3=0.f;
    const float* base = &s_big[wave*CQ*36];
    #pragma unroll 4
    for (int s = 0; s < CQ; ++s) {
      const float* sl = base + s*36;
      float t = sl[32+h] * sl[hp];
      float4 B4 = *(const float4*)&sl[16 + nb*4];
      a0 += t*B4.x; a1 += t*B4.y; a2 += t*B4.z; a3 += t*B4.w;
    }
    *(float4*)(Sc + cg*256 + hp*16 + nb*4) = make_float4(a0,a1,a2,a3);
    if (lane == 0) { Pc[cg*2] = cee0; Pc[cg*2+1] = cee1; }
  } else {
    // ---- intra-chunk quadratic scan via readlane broadcasts ----
    float y[16];
    float D0 = Dvec[0], D1 = Dvec[1];
    #pragma unroll
    for (int p = 0; p < 8; ++p) { y[p] = D0*xv[p]; y[8+p] = D1*xv[8+p]; }
    #pragma unroll 2
    for (int s = 0; s < CQ; ++s) {
      float bb[16];
      #pragma unroll
      for (int n = 0; n < 16; ++n) bb[n] = rl(Bv[n], s);
      float t0 = Cvr[0]*bb[0] + Cvr[1]*bb[1] + Cvr[2]*bb[2] + Cvr[3]*bb[3];
      float t1 = Cvr[4]*bb[4] + Cvr[5]*bb[5] + Cvr[6]*bb[6] + Cvr[7]*bb[7];
      float t2 = Cvr[8]*bb[8] + Cvr[9]*bb[9] + Cvr[10]*bb[10] + Cvr[11]*bb[11];
      float t3 = Cvr[12]*bb[12] + Cvr[13]*bb[13] + Cvr[14]*bb[14] + Cvr[15]*bb[15];
      float gg = (t0 + t1) + (t2 + t3);
      float wA = ce0 * (rl(cf0, s) * gg);
      float wB = ce1 * (rl(cf1, s) * gg);
      bool ok = (s <= lane);
      wA = ok ? wA : 0.f; wB = ok ? wB : 0.f;
      #pragma unroll
      for (int p = 0; p < 8; ++p) {
        y[p]   += wA * rl(xv[p],   s);
        y[8+p] += wB * rl(xv[8+p], s);
      }
    }
    // ---- inter-chunk contribution (state broadcast via readlane) ----
    #pragma unroll
    for (int hp = 0; hp < 16; ++hp) {
      float a = 0.f;
      #pragma unroll
      for (int n = 0; n < 16; ++n) {
        int idx = hp*16 + n;
        a += Cvr[n] * rl(sv[idx & 3], idx >> 2);
      }
      y[hp] += ((hp < 8) ? ce0 : ce1) * a;
    }
    // ---- gate, RMS norm, out-proj, +u residual ----
    float yv[16]; float ss = 0.f;
    #pragma unroll
    for (int d = 0; d < 16; ++d) {
      float zz = 0.f;
      #pragma unroll
      for (int g = 0; g < 8; ++g) zz += u[g]*w_in[d*8+g];
      float v = y[d] * (zz * sigu(zz));
      yv[d] = v; ss += v*v;
    }
    float scn = rsqrtf(ss*(1.f/16.f) + 1e-5f);
    #pragma unroll
    for (int d = 0; d < 16; ++d) yv[d] *= scn * norm_w[d];
    float og[8];
    #pragma unroll
    for (int g = 0; g < 8; ++g) {
      float a = u[g];
      #pragma unroll
      for (int d = 0; d < 16; ++d) a += yv[d]*w_out[g*16+d];
      og[g] = a;
    }
    float* gp = gf + pos*8;
    *(float4*)gp     = make_float4(og[0],og[1],og[2],og[3]);
    *(float4*)(gp+4) = make_float4(og[4],og[5],og[6],og[7]);
  }
}

__global__ __launch_bounds__(256) void k_scan(
    const float* __restrict__ Sc, const float* __restrict__ Pc,
    float* __restrict__ Stin)
{
  int b = blockIdx.x;
  int tid = threadIdx.x;           // hp*16 + n
  int h = tid >> 7;
  float st = 0.f;
  long base = (long)b * NCH;
  #pragma unroll 8
  for (int c = 0; c < NCH; ++c) {
    Stin[(base + c)*256 + tid] = st;
    st = st * Pc[(base + c)*2 + h] + Sc[(base + c)*256 + tid];
  }
}

__global__ __launch_bounds__(256) void k_detok(
    const float* __restrict__ x, const float* __restrict__ gf,
    const float* __restrict__ w_detok, const float* __restrict__ b_detok,
    float* __restrict__ out)
{
  long idx = (long)blockIdx.x * 256 + threadIdx.x;
  int b = (int)(idx >> 14);
  int l = (int)(idx & (SL-1));
  float gv[8];
  const float* gp = gf + idx*8;
  { float4 a = *(const float4*)gp, c = *(const float4*)(gp+4);
    gv[0]=a.x;gv[1]=a.y;gv[2]=a.z;gv[3]=a.w;gv[4]=c.x;gv[5]=c.y;gv[6]=c.z;gv[7]=c.w; }
  const float* xp = x + (long)b*NC*HW + l;
  float* op = out + (long)b*NC*HW + l;
  #pragma unroll 4
  for (int c = 0; c < NC; ++c) {
    float a = b_detok[c] + xp[(long)c*HW];
    #pragma unroll
    for (int g = 0; g < 8; ++g) a += gv[g]*w_detok[c*8+g];   // uniform -> s_load
    op[(long)c*HW] = a;
  }
}
} // namespace

extern "C" void kernel_launch(void* const* d_in, const int* in_sizes, int n_in,
                              void* d_out, int out_size, void* d_ws, size_t ws_size,
                              hipStream_t stream)
{
  const float* x       = (const float*)d_in[0];
  const float* w_tok   = (const float*)d_in[1];
  const float* b_tok   = (const float*)d_in[2];
  const float* w_detok = (const float*)d_in[3];
  const float* b_detok = (const float*)d_in[4];
  const float* w_in    = (const float*)d_in[5];
  const float* w_conv  = (const float*)d_in[6];
  const float* b_conv  = (const float*)d_in[7];
  const float* dt_bias = (const float*)d_in[8];
  const float* A_log   = (const float*)d_in[9];
  const float* Dvec    = (const float*)d_in[10];
  const float* norm_w  = (const float*)d_in[11];
  const float* w_out   = (const float*)d_in[12];
  float* out = (float*)d_out;

  float* ws   = (float*)d_ws;
  float* g0   = ws;
  float* gf   = g0 + (long)NB*SL*NG;
  float* Sc   = gf + (long)NB*SL*NG;
  float* Pc   = Sc + (long)NB*NCH*256;
  float* Stin = Pc + (long)NB*NCH*2;

  k_tok<<<NB*SL/256, 256, 0, stream>>>(x, w_tok, b_tok, g0);
  k_chunk<0><<<NB*NCH/WCH, 256, 0, stream>>>(g0, w_in, w_conv, b_conv, dt_bias,
                                             A_log, Dvec, norm_w, w_out,
                                             Sc, Pc, nullptr, nullptr);
  k_scan<<<NB, 256, 0, stream>>>(Sc, Pc, Stin);
  k_chunk<1><<<NB*NCH/WCH, 256, 0, stream>>>(g0, w_in, w_conv, b_conv, dt_bias,
                                             A_log, Dvec, norm_w, w_out,
                                             Sc, Pc, Stin, gf);
  k_detok<<<NB*SL/256, 256, 0, stream>>>(x, gf, w_detok, b_detok, out);
}